// Round 16
// baseline (143.226 us; speedup 1.0000x reference)
//
#include <hip/hip_runtime.h>

#define TT 2048
#define DD 1024
#define HH 16
#define DKK 64
#define BB 2

typedef __attribute__((ext_vector_type(8))) short bf16x8;
typedef __attribute__((ext_vector_type(4))) short bf16x4;
typedef __attribute__((ext_vector_type(4))) float f32x4;
typedef __attribute__((ext_vector_type(4))) unsigned short us4;
typedef __attribute__((ext_vector_type(4))) unsigned int u32x4;

__device__ __forceinline__ unsigned short f2bf(float f) {
  union { float f; unsigned int i; } v; v.f = f;
  unsigned int x = v.i;
  return (unsigned short)((x + 0x7fffu + ((x >> 16) & 1u)) >> 16);
}
__device__ __forceinline__ unsigned int cvtpk_bf16(float lo, float hi) {
  unsigned int r;
  asm("v_cvt_pk_bf16_f32 %0, %1, %2" : "=v"(r) : "v"(lo), "v"(hi));
  return r;
}
__device__ __forceinline__ void gload16(const void* g, void* l) {
  __builtin_amdgcn_global_load_lds((const __attribute__((address_space(1))) void*)g,
                                   (__attribute__((address_space(3))) void*)l,
                                   16, 0, 0);
}

#if defined(__has_builtin)
#if __has_builtin(__builtin_amdgcn_exp2f)
#define HAVE_EXP2 1
#endif
#if __has_builtin(__builtin_amdgcn_mfma_f32_16x16x16bf16_1k)
#define HAVE_MFMA16 1
#endif
#endif

__device__ __forceinline__ float fexp2(float x) {
#ifdef HAVE_EXP2
  return __builtin_amdgcn_exp2f(x);
#else
  return __builtin_exp2f(x);
#endif
}

__device__ __forceinline__ f32x4 mfma16(bf16x4 a, bf16x4 b, f32x4 c) {
#ifdef HAVE_MFMA16
  return __builtin_amdgcn_mfma_f32_16x16x16bf16_1k(a, b, c, 0, 0, 0);
#else
  asm volatile("v_mfma_f32_16x16x16_bf16 %0, %1, %2, %0\n\ts_nop 7\n\ts_nop 7"
               : "+v"(c) : "v"(a), "v"(b));
  return c;
#endif
}

// fp32 -> bf16 for W only (k,q,v conversion fused into gemm_proj staging)
__global__ __launch_bounds__(256)
void f2bW(const float* __restrict__ in, unsigned short* __restrict__ out)
{
  const int n4 = (DD * DD) / 4;  // 262144
  int i = blockIdx.x * 256 + threadIdx.x;
  const int stride = gridDim.x * 256;
  for (; i < n4; i += stride) {
    const float4 f = ((const float4*)in)[i];
    us4 o;
    o[0] = f2bf(f.x); o[1] = f2bf(f.y); o[2] = f2bf(f.z); o[3] = f2bf(f.w);
    ((us4*)out)[i] = o;
  }
}

// ---- GEMM machinery: 2-barrier double-buffered K-loop, BK=32 ----
// gemm_proj 128x64 (1536 blocks = 6/CU), gemm_out 64x64 (1024 = 4/CU).
// LDS rows 64B; XOR-swizzle (row&3)<<4. B-side: pre-swizzled global source +
// linear gload_lds dest. A-side (gemm_proj): fp32 reg-staged (fused convert),
// writer applies the swizzle on the ds_write address (both-sides rule).
// Bijective XCD swizzle (n fast): A-strip-sharing blocks stay on one XCD.

// Fused convert+K/Q/V projection: tile 128(m) x 64(n); grid (16,96) = 1536.
__global__ __launch_bounds__(256)
void gemm_proj(const float* __restrict__ kf, const float* __restrict__ qf,
               const float* __restrict__ vf, const unsigned short* __restrict__ W,
               const float* __restrict__ bias,
               unsigned short* __restrict__ Kp, unsigned short* __restrict__ Qp,
               unsigned short* __restrict__ Vt)
{
  __shared__ unsigned short lA[2][128 * 32];
  __shared__ unsigned short lB[2][64 * 32];
  const int tid = threadIdx.x;
  const int w = tid >> 6, l = tid & 63;
  const int hw = blockIdx.y * gridDim.x + blockIdx.x;     // 0..1535
  const int virt = (hw & 7) * 192 + (hw >> 3);            // bijective XCD swizzle
  const int n0 = (virt & 15) * 64;                        // 16 n-blocks
  const int my = virt >> 4;                               // 0..95 m-strips
  const int grp = my >> 5;                                // 0:K 1:Q 2:V
  const int m0 = (my & 31) * 128;
  const float* A = grp == 0 ? kf : (grp == 1 ? qf : vf);  // fp32 source
  const int wr = w >> 1, wc = w & 1;
  const int lg = l >> 4, lc = l & 15;

  f32x4 acc[4][2];
#pragma unroll
  for (int i = 0; i < 4; ++i)
#pragma unroll
    for (int j = 0; j < 2; ++j) acc[i][j] = (f32x4){0.f, 0.f, 0.f, 0.f};

  const int scolb = (((l & 3) ^ ((l >> 2) & 3)) * 16);  // B pre-swizzled source slot

  // A-staging: each thread owns 2 rows x 8 fp32 (16B bf16 after convert).
  const int arow0 = (w * 2 + 0) * 16 + (l >> 2);   // 0..127
  const int arow1 = (w * 2 + 1) * 16 + (l >> 2);
  const int asl = l & 3;                            // 16B slot within 64B row
  // swizzled LDS byte dest (matches reader's (lg*16)^((row&3)<<4))
  const int adst0 = arow0 * 64 + ((asl * 16) ^ ((arow0 & 3) << 4));
  const int adst1 = arow1 * 64 + ((asl * 16) ^ ((arow1 & 3) << 4));

  float4 areg[4];
  auto issueA = [&](int k0) {
    const float* s0 = A + (size_t)(m0 + arow0) * DD + k0 + asl * 8;
    const float* s1 = A + (size_t)(m0 + arow1) * DD + k0 + asl * 8;
    areg[0] = *(const float4*)s0;
    areg[1] = *(const float4*)(s0 + 4);
    areg[2] = *(const float4*)s1;
    areg[3] = *(const float4*)(s1 + 4);
  };
  auto writeA = [&](int buf) {
    u32x4 p0, p1;
    p0[0] = cvtpk_bf16(areg[0].x, areg[0].y);
    p0[1] = cvtpk_bf16(areg[0].z, areg[0].w);
    p0[2] = cvtpk_bf16(areg[1].x, areg[1].y);
    p0[3] = cvtpk_bf16(areg[1].z, areg[1].w);
    p1[0] = cvtpk_bf16(areg[2].x, areg[2].y);
    p1[1] = cvtpk_bf16(areg[2].z, areg[2].w);
    p1[2] = cvtpk_bf16(areg[3].x, areg[3].y);
    p1[3] = cvtpk_bf16(areg[3].z, areg[3].w);
    *(u32x4*)((char*)lA[buf] + adst0) = p0;
    *(u32x4*)((char*)lA[buf] + adst1) = p1;
  };
  auto stageB = [&](int buf, int k0) {
    const int row = w * 16 + (l >> 2);              // 4 slots x 16 rows = 64
    gload16(W + (size_t)(n0 + row) * DD + k0 + (scolb >> 1), &lB[buf][w * 512]);
  };

  issueA(0);
  stageB(0, 0);
  writeA(0);
  __syncthreads();
  int cur = 0;
#pragma unroll 1
  for (int kt = 0; kt < 32; ++kt) {
    if (kt < 31) { issueA((kt + 1) * 32); stageB(cur ^ 1, (kt + 1) * 32); }
    const char* la = (const char*)lA[cur];
    const char* lb = (const char*)lB[cur];
    bf16x8 af[4], bfr[2];
#pragma unroll
    for (int mf = 0; mf < 4; ++mf)
      af[mf] = *(const bf16x8*)(la + (wr * 64 + mf * 16 + lc) * 64 + ((lg * 16) ^ ((lc & 3) << 4)));
#pragma unroll
    for (int nf = 0; nf < 2; ++nf)
      bfr[nf] = *(const bf16x8*)(lb + (wc * 32 + nf * 16 + lc) * 64 + ((lg * 16) ^ ((lc & 3) << 4)));
#pragma unroll
    for (int mf = 0; mf < 4; ++mf)
#pragma unroll
      for (int nf = 0; nf < 2; ++nf)
        acc[mf][nf] = __builtin_amdgcn_mfma_f32_16x16x32_bf16(af[mf], bfr[nf], acc[mf][nf], 0, 0, 0);
    if (kt < 31) writeA(cur ^ 1);   // buf^1 readers finished at previous barrier
    __syncthreads();
    cur ^= 1;
  }

  // Q gets 1/sqrt(DK) * log2(e) folded in (attn softmax runs in exp2 domain)
  const float scale = (grp == 1) ? 0.125f * 1.4426950408889634f : 1.0f;
#pragma unroll
  for (int nf = 0; nf < 2; ++nf) {
    const int colg = n0 + wc * 32 + nf * 16 + lc;
    const float bv = bias[colg];
#pragma unroll
    for (int mf = 0; mf < 4; ++mf) {
      const int rowg = m0 + wr * 64 + mf * 16 + lg * 4;
      if (grp < 2) {
        unsigned short* C = grp == 0 ? Kp : Qp;
#pragma unroll
        for (int r = 0; r < 4; ++r)
          C[(size_t)(rowg + r) * DD + colg] = f2bf(scale * (acc[mf][nf][r] + bv));
      } else {
        const int bb = rowg >> 11, t = rowg & (TT - 1);
        const int hh = colg >> 6, dk = colg & 63;
        us4 pk;
#pragma unroll
        for (int r = 0; r < 4; ++r) pk[r] = f2bf(acc[mf][nf][r] + bv);
        *(us4*)&Vt[((size_t)((bb * HH + hh) * DKK + dk)) * TT + t] = pk;
      }
    }
  }
}

// Final projection: C(fp32) = A @ W^T + bias; tile 64x64; grid (16,64)=1024.
__global__ __launch_bounds__(256)
void gemm_out(const unsigned short* __restrict__ A, const unsigned short* __restrict__ W,
              const float* __restrict__ bias, float* __restrict__ Cf)
{
  __shared__ unsigned short lA[2][64 * 32];
  __shared__ unsigned short lB[2][64 * 32];
  const int tid = threadIdx.x;
  const int w = tid >> 6, l = tid & 63;
  const int hw = blockIdx.y * gridDim.x + blockIdx.x;     // 0..1023
  const int virt = (hw & 7) * 128 + (hw >> 3);            // bijective XCD swizzle
  const int n0 = (virt & 15) * 64, m0 = (virt >> 4) * 64;
  const int wr = w >> 1, wc = w & 1;
  const int lg = l >> 4, lc = l & 15;

  f32x4 acc[2][2];
#pragma unroll
  for (int i = 0; i < 2; ++i)
#pragma unroll
    for (int j = 0; j < 2; ++j) acc[i][j] = (f32x4){0.f, 0.f, 0.f, 0.f};

  const int scolb = (((l & 3) ^ ((l >> 2) & 3)) * 16);

  auto stage = [&](int buf, int k0) {
    const int row = w * 16 + (l >> 2);                    // 4 slots x 16 rows
    gload16(A + (size_t)(m0 + row) * DD + k0 + (scolb >> 1), &lA[buf][w * 512]);
    gload16(W + (size_t)(n0 + row) * DD + k0 + (scolb >> 1), &lB[buf][w * 512]);
  };

  stage(0, 0);
  __syncthreads();
  int cur = 0;
#pragma unroll 1
  for (int kt = 0; kt < 32; ++kt) {
    if (kt < 31) stage(cur ^ 1, (kt + 1) * 32);
    const char* la = (const char*)lA[cur];
    const char* lb = (const char*)lB[cur];
    bf16x8 af[2], bfr[2];
#pragma unroll
    for (int mf = 0; mf < 2; ++mf)
      af[mf] = *(const bf16x8*)(la + (wr * 32 + mf * 16 + lc) * 64 + ((lg * 16) ^ ((lc & 3) << 4)));
#pragma unroll
    for (int nf = 0; nf < 2; ++nf)
      bfr[nf] = *(const bf16x8*)(lb + (wc * 32 + nf * 16 + lc) * 64 + ((lg * 16) ^ ((lc & 3) << 4)));
#pragma unroll
    for (int mf = 0; mf < 2; ++mf)
#pragma unroll
      for (int nf = 0; nf < 2; ++nf)
        acc[mf][nf] = __builtin_amdgcn_mfma_f32_16x16x32_bf16(af[mf], bfr[nf], acc[mf][nf], 0, 0, 0);
    __syncthreads();
    cur ^= 1;
  }

#pragma unroll
  for (int nf = 0; nf < 2; ++nf) {
    const int colg = n0 + wc * 32 + nf * 16 + lc;
    const float bv = bias[colg];
#pragma unroll
    for (int mf = 0; mf < 2; ++mf) {
      const int rowg = m0 + wr * 32 + mf * 16 + lg * 4;
#pragma unroll
      for (int r = 0; r < 4; ++r)
        Cf[(size_t)(rowg + r) * DD + colg] = acc[mf][nf][r] + bv;
    }
  }
}

// Flash attention (round-13/14 version, unchanged): swapped-operand QK^T,
// in-register P, exp2-domain softmax, T13 defer-rescale, deferred lsum
// reduce. QBLK=64, grid (32,32), heavy-first.
__global__ __launch_bounds__(256)
void attn(const unsigned short* __restrict__ Qp,
          const unsigned short* __restrict__ Kp,
          const unsigned short* __restrict__ Vt,
          const int* __restrict__ maskp,
          const int* __restrict__ causalp,
          unsigned short* __restrict__ Oc)
{
  __shared__ unsigned short Kl[2][64 * 64];
  __shared__ unsigned short Vl[2][64 * 64];
  const int tid = threadIdx.x;
  const int w = tid >> 6, l = tid & 63;
  const int bh = blockIdx.x;
  const int q0 = (31 - blockIdx.y) * 64;
  const int b = bh >> 4, h = bh & 15;
  const int lg = l >> 4, lc = l & 15;
  const int causal = causalp[0];
  const int qr = q0 + w * 16 + lc;          // this lane's q-row

  bf16x8 qf[2];
  {
    const unsigned short* qp = Qp + (size_t)(b * TT + qr) * DD + h * DKK + lg * 8;
    qf[0] = *(const bf16x8*)qp;
    qf[1] = *(const bf16x8*)(qp + 32);
  }
  f32x4 o[4];
#pragma unroll
  for (int nfo = 0; nfo < 4; ++nfo) o[nfo] = (f32x4){0.f, 0.f, 0.f, 0.f};
  float m = -1e30f, lsum = 0.f;              // lsum: per-lane partial

  const int swz = ((l & 7) ^ (l >> 3)) * 16;
  int kcoff[2], vcoff[4];
#pragma unroll
  for (int kk = 0; kk < 2; ++kk) kcoff[kk] = (kk * 64 + lg * 16) ^ ((lc & 7) << 4);
#pragma unroll
  for (int nfk = 0; nfk < 4; ++nfk) vcoff[nfk] = (nfk * 32 + lg * 8) ^ ((lc & 7) << 4);
  const int rowb = lc * 128;
  const int* mrow = maskp + b * TT;

  auto stage = [&](int buf, int c0) {
#pragma unroll
    for (int cc = 0; cc < 2; ++cc) {
      const int slot = w * 2 + cc;
      const int rr = slot * 8 + (l >> 3);
      gload16(Kp + (size_t)(b * TT + c0 + rr) * DD + h * DKK + (swz >> 1), &Kl[buf][slot * 512]);
      gload16(Vt + (size_t)((b * HH + h) * DKK + rr) * TT + c0 + (swz >> 1), &Vl[buf][slot * 512]);
    }
  };

  const int ntiles = (causal ? (q0 + 64) : TT) >> 6;
  stage(0, 0);
  __syncthreads();
  int cur = 0;
#pragma unroll 1
  for (int t = 0; t < ntiles; ++t) {
    if (t + 1 < ntiles) stage(cur ^ 1, (t + 1) * 64);
    const int c0 = t * 64;
    const char* kl = (const char*)Kl[cur];
    const char* vl = (const char*)Vl[cur];

    f32x4 s[4];
#pragma unroll
    for (int nf = 0; nf < 4; ++nf) s[nf] = (f32x4){0.f, 0.f, 0.f, 0.f};
#pragma unroll
    for (int nf = 0; nf < 4; ++nf)
#pragma unroll
      for (int kk = 0; kk < 2; ++kk) {
        bf16x8 kf = *(const bf16x8*)(kl + rowb + kcoff[kk] + nf * 2048);
        s[nf] = __builtin_amdgcn_mfma_f32_16x16x32_bf16(kf, qf[kk], s[nf], 0, 0, 0);
      }

    const unsigned long long bal = __ballot(mrow[c0 + l] != 0);
    if (bal != ~0ull) {
#pragma unroll
      for (int nf = 0; nf < 4; ++nf) {
        const int4 mv = *(const int4*)&mrow[c0 + nf * 16 + lg * 4];
        const int mvr[4] = {mv.x, mv.y, mv.z, mv.w};
#pragma unroll
        for (int r = 0; r < 4; ++r)
          if (mvr[r] == 0) s[nf][r] = -1e30f;
      }
    }
    if (causal && (t == ntiles - 1)) {
#pragma unroll
      for (int nf = 0; nf < 4; ++nf)
#pragma unroll
        for (int r = 0; r < 4; ++r) {
          const int kg = c0 + nf * 16 + lg * 4 + r;
          if (kg > qr) s[nf][r] = -1e30f;
        }
    }

    float pm = fmaxf(fmaxf(fmaxf(s[0][0], s[0][1]), fmaxf(s[0][2], s[0][3])),
                     fmaxf(fmaxf(s[1][0], s[1][1]), fmaxf(s[1][2], s[1][3])));
    pm = fmaxf(pm, fmaxf(fmaxf(fmaxf(s[2][0], s[2][1]), fmaxf(s[2][2], s[2][3])),
                         fmaxf(fmaxf(s[3][0], s[3][1]), fmaxf(s[3][2], s[3][3]))));
    pm = fmaxf(pm, __shfl_xor(pm, 16, 64));
    pm = fmaxf(pm, __shfl_xor(pm, 32, 64));

    // T13 defer-rescale
    if (!__all((m > -1e28f) && (pm <= m + 8.0f))) {
      const float mn = fmaxf(fmaxf(m, pm), -1e28f);
      const float al = fexp2(m - mn);
      m = mn;
      float alr[4];
#pragma unroll
      for (int r = 0; r < 4; ++r) alr[r] = __shfl(al, lg * 4 + r, 64);
#pragma unroll
      for (int nfo = 0; nfo < 4; ++nfo)
#pragma unroll
        for (int r = 0; r < 4; ++r) o[nfo][r] *= alr[r];
      lsum *= al;
    }

    float ps = 0.f;
    bf16x4 pa[4];
#pragma unroll
    for (int nf = 0; nf < 4; ++nf) {
      const float p0 = fexp2(s[nf][0] - m);
      const float p1 = fexp2(s[nf][1] - m);
      const float p2 = fexp2(s[nf][2] - m);
      const float p3 = fexp2(s[nf][3] - m);
      ps += (p0 + p1) + (p2 + p3);
      union { unsigned int u[2]; bf16x4 v; } pk;
      pk.u[0] = cvtpk_bf16(p0, p1);
      pk.u[1] = cvtpk_bf16(p2, p3);
      pa[nf] = pk.v;
    }
    lsum += ps;   // per-lane partial; lg-reduce deferred to epilogue

#pragma unroll
    for (int nfo = 0; nfo < 4; ++nfo)
#pragma unroll
      for (int nfk = 0; nfk < 4; ++nfk) {
        bf16x4 vb = *(const bf16x4*)(vl + rowb + vcoff[nfk] + nfo * 2048);
        o[nfo] = mfma16(pa[nfk], vb, o[nfo]);
      }

    __syncthreads();
    cur ^= 1;
  }

  lsum += __shfl_xor(lsum, 16, 64);
  lsum += __shfl_xor(lsum, 32, 64);
  float linv[4];
#pragma unroll
  for (int r = 0; r < 4; ++r) linv[r] = 1.0f / __shfl(lsum, lg * 4 + r, 64);
#pragma unroll
  for (int nfo = 0; nfo < 4; ++nfo) {
    const int dg = h * DKK + nfo * 16 + lc;
#pragma unroll
    for (int r = 0; r < 4; ++r) {
      const int qg = q0 + w * 16 + lg * 4 + r;
      Oc[(size_t)(b * TT + qg) * DD + dg] = f2bf(o[nfo][r] * linv[r]);
    }
  }
}

extern "C" void kernel_launch(void* const* d_in, const int* in_sizes, int n_in,
                              void* d_out, int out_size, void* d_ws, size_t ws_size,
                              hipStream_t stream)
{
  (void)in_sizes; (void)n_in; (void)out_size; (void)ws_size;
  const float* kf = (const float*)d_in[0];
  const float* qf = (const float*)d_in[1];
  const float* vf = (const float*)d_in[2];
  const int* mask = (const int*)d_in[3];
  const int* causal = (const int*)d_in[4];
  const float* Wf = (const float*)d_in[5];
  const float* bf = (const float*)d_in[6];

  const size_t MB = 1024 * 1024;
  char* ws = (char*)d_ws;
  unsigned short* Wb = (unsigned short*)(ws);                 // 2 MiB
  unsigned short* Kp = (unsigned short*)(ws + 2 * MB);        // 8 MiB
  unsigned short* Qp = (unsigned short*)(ws + 10 * MB);       // 8 MiB
  unsigned short* Vt = (unsigned short*)(ws + 18 * MB);       // 8 MiB
  unsigned short* Oc = (unsigned short*)(ws + 26 * MB);       // 8 MiB

  f2bW<<<dim3(512), dim3(256), 0, stream>>>(Wf, Wb);
  gemm_proj<<<dim3(16, 96), dim3(256), 0, stream>>>(kf, qf, vf, Wb, bf, Kp, Qp, Vt);
  attn<<<dim3(32, 32), dim3(256), 0, stream>>>(Qp, Kp, Vt, mask, causal, Oc);
  gemm_out<<<dim3(16, 64), dim3(256), 0, stream>>>(Oc, Wb, bf, (float*)d_out);
}

// Round 17
// 130.873 us; speedup vs baseline: 1.0944x; 1.0944x over previous
//
#include <hip/hip_runtime.h>

#define TT 2048
#define DD 1024
#define HH 16
#define DKK 64
#define BB 2

typedef __attribute__((ext_vector_type(8))) short bf16x8;
typedef __attribute__((ext_vector_type(4))) short bf16x4;
typedef __attribute__((ext_vector_type(4))) float f32x4;
typedef __attribute__((ext_vector_type(4))) unsigned short us4;

__device__ __forceinline__ unsigned short f2bf(float f) {
  union { float f; unsigned int i; } v; v.f = f;
  unsigned int x = v.i;
  return (unsigned short)((x + 0x7fffu + ((x >> 16) & 1u)) >> 16);
}
__device__ __forceinline__ unsigned int cvtpk_bf16(float lo, float hi) {
  unsigned int r;
  asm("v_cvt_pk_bf16_f32 %0, %1, %2" : "=v"(r) : "v"(lo), "v"(hi));
  return r;
}
__device__ __forceinline__ void gload16(const void* g, void* l) {
  __builtin_amdgcn_global_load_lds((const __attribute__((address_space(1))) void*)g,
                                   (__attribute__((address_space(3))) void*)l,
                                   16, 0, 0);
}

#if defined(__has_builtin)
#if __has_builtin(__builtin_amdgcn_exp2f)
#define HAVE_EXP2 1
#endif
#if __has_builtin(__builtin_amdgcn_mfma_f32_16x16x16bf16_1k)
#define HAVE_MFMA16 1
#endif
#endif

__device__ __forceinline__ float fexp2(float x) {
#ifdef HAVE_EXP2
  return __builtin_amdgcn_exp2f(x);
#else
  return __builtin_exp2f(x);
#endif
}

__device__ __forceinline__ f32x4 mfma16(bf16x4 a, bf16x4 b, f32x4 c) {
#ifdef HAVE_MFMA16
  return __builtin_amdgcn_mfma_f32_16x16x16bf16_1k(a, b, c, 0, 0, 0);
#else
  asm volatile("v_mfma_f32_16x16x16_bf16 %0, %1, %2, %0\n\ts_nop 7\n\ts_nop 7"
               : "+v"(c) : "v"(a), "v"(b));
  return c;
#endif
}

// fp32 -> bf16 for k,q,v,W in one dispatch (restored r14 version; this pass
// is HBM-BW-bound at ~6.7 TB/s — fusing it into the GEMM regressed, r16)
__global__ __launch_bounds__(256)
void f2b_all(const float* __restrict__ k, const float* __restrict__ q,
             const float* __restrict__ v, const float* __restrict__ W,
             unsigned short* __restrict__ kb, unsigned short* __restrict__ qb,
             unsigned short* __restrict__ vb, unsigned short* __restrict__ Wb)
{
  const int n1 = (BB * TT * DD) / 4;   // 1048576 float4s per tensor
  const int nW = (DD * DD) / 4;        // 262144
  const int total = 3 * n1 + nW;
  int i = blockIdx.x * 256 + threadIdx.x;
  const int stride = gridDim.x * 256;
  for (; i < total; i += stride) {
    const float* src; unsigned short* dst; int j = i;
    if (j < n1)            { src = k; dst = kb; }
    else if (j < 2 * n1)   { src = q; dst = qb; j -= n1; }
    else if (j < 3 * n1)   { src = v; dst = vb; j -= 2 * n1; }
    else                   { src = W; dst = Wb; j -= 3 * n1; }
    const float4 f = ((const float4*)src)[j];
    us4 o;
    o[0] = f2bf(f.x); o[1] = f2bf(f.y); o[2] = f2bf(f.z); o[3] = f2bf(f.w);
    ((us4*)dst)[j] = o;
  }
}

// ---- GEMM machinery: 2-barrier double-buffered K-loop, BK=32 ----
// Both GEMMs 64x64 tiles for max TLP (latency-bound: no pipe >31%).
// gemm_proj: grid (16,192)=3072 blocks (12/CU queued, LDS 16KB -> ~10
// co-resident). gemm_out: grid (16,64)=1024. LDS rows 64B; XOR-swizzle
// (row&3)<<4 via pre-swizzled global source + linear gload_lds dest.
// Bijective XCD swizzle (n fast): A-strip-sharing blocks share an XCD L2.

// Fused K/Q/V projection: tile 64x64.
__global__ __launch_bounds__(256)
void gemm_proj(const unsigned short* __restrict__ kb, const unsigned short* __restrict__ qb,
               const unsigned short* __restrict__ vb, const unsigned short* __restrict__ W,
               const float* __restrict__ bias,
               unsigned short* __restrict__ Kp, unsigned short* __restrict__ Qp,
               unsigned short* __restrict__ Vt)
{
  __shared__ unsigned short lA[2][64 * 32];
  __shared__ unsigned short lB[2][64 * 32];
  const int tid = threadIdx.x;
  const int w = tid >> 6, l = tid & 63;
  const int hw = blockIdx.y * gridDim.x + blockIdx.x;     // 0..3071
  const int virt = (hw & 7) * 384 + (hw >> 3);            // bijective XCD swizzle
  const int n0 = (virt & 15) * 64;                        // 16 n-blocks
  const int my = virt >> 4;                               // 0..191 m-strips
  const int grp = my >> 6;                                // 0:K 1:Q 2:V
  const int m0 = (my & 63) * 64;
  const unsigned short* A = grp == 0 ? kb : (grp == 1 ? qb : vb);
  const int wr = w >> 1, wc = w & 1;
  const int lg = l >> 4, lc = l & 15;

  f32x4 acc[2][2];
#pragma unroll
  for (int i = 0; i < 2; ++i)
#pragma unroll
    for (int j = 0; j < 2; ++j) acc[i][j] = (f32x4){0.f, 0.f, 0.f, 0.f};

  const int scolb = (((l & 3) ^ ((l >> 2) & 3)) * 16);  // pre-swizzled source slot

  auto stage = [&](int buf, int k0) {
    const int row = w * 16 + (l >> 2);                  // 4 slots x 16 rows = 64
    gload16(A + (size_t)(m0 + row) * DD + k0 + (scolb >> 1), &lA[buf][w * 512]);
    gload16(W + (size_t)(n0 + row) * DD + k0 + (scolb >> 1), &lB[buf][w * 512]);
  };

  stage(0, 0);
  __syncthreads();
  int cur = 0;
#pragma unroll 1
  for (int kt = 0; kt < 32; ++kt) {
    if (kt < 31) stage(cur ^ 1, (kt + 1) * 32);
    const char* la = (const char*)lA[cur];
    const char* lb = (const char*)lB[cur];
    bf16x8 af[2], bfr[2];
#pragma unroll
    for (int mf = 0; mf < 2; ++mf)
      af[mf] = *(const bf16x8*)(la + (wr * 32 + mf * 16 + lc) * 64 + ((lg * 16) ^ ((lc & 3) << 4)));
#pragma unroll
    for (int nf = 0; nf < 2; ++nf)
      bfr[nf] = *(const bf16x8*)(lb + (wc * 32 + nf * 16 + lc) * 64 + ((lg * 16) ^ ((lc & 3) << 4)));
#pragma unroll
    for (int mf = 0; mf < 2; ++mf)
#pragma unroll
      for (int nf = 0; nf < 2; ++nf)
        acc[mf][nf] = __builtin_amdgcn_mfma_f32_16x16x32_bf16(af[mf], bfr[nf], acc[mf][nf], 0, 0, 0);
    __syncthreads();
    cur ^= 1;
  }

  // Q gets 1/sqrt(DK) * log2(e) folded in (attn softmax runs in exp2 domain)
  const float scale = (grp == 1) ? 0.125f * 1.4426950408889634f : 1.0f;
#pragma unroll
  for (int nf = 0; nf < 2; ++nf) {
    const int colg = n0 + wc * 32 + nf * 16 + lc;
    const float bv = bias[colg];
#pragma unroll
    for (int mf = 0; mf < 2; ++mf) {
      const int rowg = m0 + wr * 32 + mf * 16 + lg * 4;
      if (grp < 2) {
        unsigned short* C = grp == 0 ? Kp : Qp;
#pragma unroll
        for (int r = 0; r < 4; ++r)
          C[(size_t)(rowg + r) * DD + colg] = f2bf(scale * (acc[mf][nf][r] + bv));
      } else {
        const int bb = rowg >> 11, t = rowg & (TT - 1);
        const int hh = colg >> 6, dk = colg & 63;
        us4 pk;
#pragma unroll
        for (int r = 0; r < 4; ++r) pk[r] = f2bf(acc[mf][nf][r] + bv);
        *(us4*)&Vt[((size_t)((bb * HH + hh) * DKK + dk)) * TT + t] = pk;
      }
    }
  }
}

// Final projection: C(fp32) = A @ W^T + bias; tile 64x64; grid (16,64)=1024.
__global__ __launch_bounds__(256)
void gemm_out(const unsigned short* __restrict__ A, const unsigned short* __restrict__ W,
              const float* __restrict__ bias, float* __restrict__ Cf)
{
  __shared__ unsigned short lA[2][64 * 32];
  __shared__ unsigned short lB[2][64 * 32];
  const int tid = threadIdx.x;
  const int w = tid >> 6, l = tid & 63;
  const int hw = blockIdx.y * gridDim.x + blockIdx.x;     // 0..1023
  const int virt = (hw & 7) * 128 + (hw >> 3);            // bijective XCD swizzle
  const int n0 = (virt & 15) * 64, m0 = (virt >> 4) * 64;
  const int wr = w >> 1, wc = w & 1;
  const int lg = l >> 4, lc = l & 15;

  f32x4 acc[2][2];
#pragma unroll
  for (int i = 0; i < 2; ++i)
#pragma unroll
    for (int j = 0; j < 2; ++j) acc[i][j] = (f32x4){0.f, 0.f, 0.f, 0.f};

  const int scolb = (((l & 3) ^ ((l >> 2) & 3)) * 16);

  auto stage = [&](int buf, int k0) {
    const int row = w * 16 + (l >> 2);                    // 4 slots x 16 rows
    gload16(A + (size_t)(m0 + row) * DD + k0 + (scolb >> 1), &lA[buf][w * 512]);
    gload16(W + (size_t)(n0 + row) * DD + k0 + (scolb >> 1), &lB[buf][w * 512]);
  };

  stage(0, 0);
  __syncthreads();
  int cur = 0;
#pragma unroll 1
  for (int kt = 0; kt < 32; ++kt) {
    if (kt < 31) stage(cur ^ 1, (kt + 1) * 32);
    const char* la = (const char*)lA[cur];
    const char* lb = (const char*)lB[cur];
    bf16x8 af[2], bfr[2];
#pragma unroll
    for (int mf = 0; mf < 2; ++mf)
      af[mf] = *(const bf16x8*)(la + (wr * 32 + mf * 16 + lc) * 64 + ((lg * 16) ^ ((lc & 3) << 4)));
#pragma unroll
    for (int nf = 0; nf < 2; ++nf)
      bfr[nf] = *(const bf16x8*)(lb + (wc * 32 + nf * 16 + lc) * 64 + ((lg * 16) ^ ((lc & 3) << 4)));
#pragma unroll
    for (int mf = 0; mf < 2; ++mf)
#pragma unroll
      for (int nf = 0; nf < 2; ++nf)
        acc[mf][nf] = __builtin_amdgcn_mfma_f32_16x16x32_bf16(af[mf], bfr[nf], acc[mf][nf], 0, 0, 0);
    __syncthreads();
    cur ^= 1;
  }

#pragma unroll
  for (int nf = 0; nf < 2; ++nf) {
    const int colg = n0 + wc * 32 + nf * 16 + lc;
    const float bv = bias[colg];
#pragma unroll
    for (int mf = 0; mf < 2; ++mf) {
      const int rowg = m0 + wr * 32 + mf * 16 + lg * 4;
#pragma unroll
      for (int r = 0; r < 4; ++r)
        Cf[(size_t)(rowg + r) * DD + colg] = acc[mf][nf][r] + bv;
    }
  }
}

// Flash attention (r13/r14 proven body) + hoisted mask scan: one upfront
// block-wide scan sets a uniform flag; all-alive masks (the common case)
// skip the per-tile ballot + global mask load entirely.
__global__ __launch_bounds__(256)
void attn(const unsigned short* __restrict__ Qp,
          const unsigned short* __restrict__ Kp,
          const unsigned short* __restrict__ Vt,
          const int* __restrict__ maskp,
          const int* __restrict__ causalp,
          unsigned short* __restrict__ Oc)
{
  __shared__ unsigned short Kl[2][64 * 64];
  __shared__ unsigned short Vl[2][64 * 64];
  __shared__ int mflag;
  const int tid = threadIdx.x;
  const int w = tid >> 6, l = tid & 63;
  const int bh = blockIdx.x;
  const int q0 = (31 - blockIdx.y) * 64;
  const int b = bh >> 4, h = bh & 15;
  const int lg = l >> 4, lc = l & 15;
  const int causal = causalp[0];
  const int qr = q0 + w * 16 + lc;          // this lane's q-row

  bf16x8 qf[2];
  {
    const unsigned short* qp = Qp + (size_t)(b * TT + qr) * DD + h * DKK + lg * 8;
    qf[0] = *(const bf16x8*)qp;
    qf[1] = *(const bf16x8*)(qp + 32);
  }
  f32x4 o[4];
#pragma unroll
  for (int nfo = 0; nfo < 4; ++nfo) o[nfo] = (f32x4){0.f, 0.f, 0.f, 0.f};
  float m = -1e30f, lsum = 0.f;              // lsum: per-lane partial

  const int swz = ((l & 7) ^ (l >> 3)) * 16;
  int kcoff[2], vcoff[4];
#pragma unroll
  for (int kk = 0; kk < 2; ++kk) kcoff[kk] = (kk * 64 + lg * 16) ^ ((lc & 7) << 4);
#pragma unroll
  for (int nfk = 0; nfk < 4; ++nfk) vcoff[nfk] = (nfk * 32 + lg * 8) ^ ((lc & 7) << 4);
  const int rowb = lc * 128;
  const int* mrow = maskp + b * TT;

  auto stage = [&](int buf, int c0) {
#pragma unroll
    for (int cc = 0; cc < 2; ++cc) {
      const int slot = w * 2 + cc;
      const int rr = slot * 8 + (l >> 3);
      gload16(Kp + (size_t)(b * TT + c0 + rr) * DD + h * DKK + (swz >> 1), &Kl[buf][slot * 512]);
      gload16(Vt + (size_t)((b * HH + h) * DKK + rr) * TT + c0 + (swz >> 1), &Vl[buf][slot * 512]);
    }
  };

  // hoisted mask scan: does this batch row have ANY dead position?
  if (tid == 0) mflag = 0;
  __syncthreads();
  {
    int az = 0;
#pragma unroll
    for (int i = 0; i < TT / 256; ++i)
      az |= (mrow[tid + i * 256] == 0) ? 1 : 0;
    if (az) mflag = 1;
  }

  const int ntiles = (causal ? (q0 + 64) : TT) >> 6;
  stage(0, 0);
  __syncthreads();                 // staging done; mflag published
  const bool havemask = (mflag != 0);
  int cur = 0;
#pragma unroll 1
  for (int t = 0; t < ntiles; ++t) {
    if (t + 1 < ntiles) stage(cur ^ 1, (t + 1) * 64);
    const int c0 = t * 64;
    const char* kl = (const char*)Kl[cur];
    const char* vl = (const char*)Vl[cur];

    f32x4 s[4];
#pragma unroll
    for (int nf = 0; nf < 4; ++nf) s[nf] = (f32x4){0.f, 0.f, 0.f, 0.f};
#pragma unroll
    for (int nf = 0; nf < 4; ++nf)
#pragma unroll
      for (int kk = 0; kk < 2; ++kk) {
        bf16x8 kf = *(const bf16x8*)(kl + rowb + kcoff[kk] + nf * 2048);
        s[nf] = __builtin_amdgcn_mfma_f32_16x16x32_bf16(kf, qf[kk], s[nf], 0, 0, 0);
      }

    if (havemask) {
      const unsigned long long bal = __ballot(mrow[c0 + l] != 0);
      if (bal != ~0ull) {
#pragma unroll
        for (int nf = 0; nf < 4; ++nf) {
          const int4 mv = *(const int4*)&mrow[c0 + nf * 16 + lg * 4];
          const int mvr[4] = {mv.x, mv.y, mv.z, mv.w};
#pragma unroll
          for (int r = 0; r < 4; ++r)
            if (mvr[r] == 0) s[nf][r] = -1e30f;
        }
      }
    }
    if (causal && (t == ntiles - 1)) {
#pragma unroll
      for (int nf = 0; nf < 4; ++nf)
#pragma unroll
        for (int r = 0; r < 4; ++r) {
          const int kg = c0 + nf * 16 + lg * 4 + r;
          if (kg > qr) s[nf][r] = -1e30f;
        }
    }

    float pm = fmaxf(fmaxf(fmaxf(s[0][0], s[0][1]), fmaxf(s[0][2], s[0][3])),
                     fmaxf(fmaxf(s[1][0], s[1][1]), fmaxf(s[1][2], s[1][3])));
    pm = fmaxf(pm, fmaxf(fmaxf(fmaxf(s[2][0], s[2][1]), fmaxf(s[2][2], s[2][3])),
                         fmaxf(fmaxf(s[3][0], s[3][1]), fmaxf(s[3][2], s[3][3]))));
    pm = fmaxf(pm, __shfl_xor(pm, 16, 64));
    pm = fmaxf(pm, __shfl_xor(pm, 32, 64));

    // T13 defer-rescale
    if (!__all((m > -1e28f) && (pm <= m + 8.0f))) {
      const float mn = fmaxf(fmaxf(m, pm), -1e28f);
      const float al = fexp2(m - mn);
      m = mn;
      float alr[4];
#pragma unroll
      for (int r = 0; r < 4; ++r) alr[r] = __shfl(al, lg * 4 + r, 64);
#pragma unroll
      for (int nfo = 0; nfo < 4; ++nfo)
#pragma unroll
        for (int r = 0; r < 4; ++r) o[nfo][r] *= alr[r];
      lsum *= al;
    }

    float ps = 0.f;
    bf16x4 pa[4];
#pragma unroll
    for (int nf = 0; nf < 4; ++nf) {
      const float p0 = fexp2(s[nf][0] - m);
      const float p1 = fexp2(s[nf][1] - m);
      const float p2 = fexp2(s[nf][2] - m);
      const float p3 = fexp2(s[nf][3] - m);
      ps += (p0 + p1) + (p2 + p3);
      union { unsigned int u[2]; bf16x4 v; } pk;
      pk.u[0] = cvtpk_bf16(p0, p1);
      pk.u[1] = cvtpk_bf16(p2, p3);
      pa[nf] = pk.v;
    }
    lsum += ps;   // per-lane partial; lg-reduce deferred to epilogue

#pragma unroll
    for (int nfo = 0; nfo < 4; ++nfo)
#pragma unroll
      for (int nfk = 0; nfk < 4; ++nfk) {
        bf16x4 vb = *(const bf16x4*)(vl + rowb + vcoff[nfk] + nfo * 2048);
        o[nfo] = mfma16(pa[nfk], vb, o[nfo]);
      }

    __syncthreads();
    cur ^= 1;
  }

  lsum += __shfl_xor(lsum, 16, 64);
  lsum += __shfl_xor(lsum, 32, 64);
  float linv[4];
#pragma unroll
  for (int r = 0; r < 4; ++r) linv[r] = 1.0f / __shfl(lsum, lg * 4 + r, 64);
#pragma unroll
  for (int nfo = 0; nfo < 4; ++nfo) {
    const int dg = h * DKK + nfo * 16 + lc;
#pragma unroll
    for (int r = 0; r < 4; ++r) {
      const int qg = q0 + w * 16 + lg * 4 + r;
      Oc[(size_t)(b * TT + qg) * DD + dg] = f2bf(o[nfo][r] * linv[r]);
    }
  }
}

extern "C" void kernel_launch(void* const* d_in, const int* in_sizes, int n_in,
                              void* d_out, int out_size, void* d_ws, size_t ws_size,
                              hipStream_t stream)
{
  (void)in_sizes; (void)n_in; (void)out_size; (void)ws_size;
  const float* kf = (const float*)d_in[0];
  const float* qf = (const float*)d_in[1];
  const float* vf = (const float*)d_in[2];
  const int* mask = (const int*)d_in[3];
  const int* causal = (const int*)d_in[4];
  const float* Wf = (const float*)d_in[5];
  const float* bf = (const float*)d_in[6];

  const size_t MB = 1024 * 1024;
  char* ws = (char*)d_ws;
  unsigned short* kb = (unsigned short*)(ws);                 // 8 MiB
  unsigned short* qb = (unsigned short*)(ws + 8 * MB);        // 8 MiB
  unsigned short* vb = (unsigned short*)(ws + 16 * MB);       // 8 MiB
  unsigned short* Wb = (unsigned short*)(ws + 24 * MB);       // 2 MiB
  unsigned short* Kp = (unsigned short*)(ws + 26 * MB);       // 8 MiB
  unsigned short* Qp = (unsigned short*)(ws + 34 * MB);       // 8 MiB
  unsigned short* Vt = (unsigned short*)(ws + 42 * MB);       // 8 MiB
  unsigned short* Oc = kb;  // kb dead after projections

  f2b_all<<<dim3(2048), dim3(256), 0, stream>>>(kf, qf, vf, Wf, kb, qb, vb, Wb);
  gemm_proj<<<dim3(16, 192), dim3(256), 0, stream>>>(kb, qb, vb, Wb, bf, Kp, Qp, Vt);
  attn<<<dim3(32, 32), dim3(256), 0, stream>>>(Qp, Kp, Vt, mask, causal, Oc);
  gemm_out<<<dim3(16, 64), dim3(256), 0, stream>>>(Oc, Wb, bf, (float*)d_out);
}

// Round 20
// 129.156 us; speedup vs baseline: 1.1089x; 1.0133x over previous
//
#include <hip/hip_runtime.h>

#define TT 2048
#define DD 1024
#define HH 16
#define DKK 64
#define BB 2

typedef __attribute__((ext_vector_type(8))) short bf16x8;
typedef __attribute__((ext_vector_type(4))) short bf16x4;
typedef __attribute__((ext_vector_type(4))) float f32x4;
typedef __attribute__((ext_vector_type(4))) unsigned short us4;
typedef __attribute__((ext_vector_type(4))) unsigned int u32x4;

__device__ __forceinline__ unsigned short f2bf(float f) {
  union { float f; unsigned int i; } v; v.f = f;
  unsigned int x = v.i;
  return (unsigned short)((x + 0x7fffu + ((x >> 16) & 1u)) >> 16);
}
__device__ __forceinline__ unsigned int cvtpk_bf16(float lo, float hi) {
  unsigned int r;
  asm("v_cvt_pk_bf16_f32 %0, %1, %2" : "=v"(r) : "v"(lo), "v"(hi));
  return r;
}
__device__ __forceinline__ void gload16(const void* g, void* l) {
  __builtin_amdgcn_global_load_lds((const __attribute__((address_space(1))) void*)g,
                                   (__attribute__((address_space(3))) void*)l,
                                   16, 0, 0);
}

#if defined(__has_builtin)
#if __has_builtin(__builtin_amdgcn_exp2f)
#define HAVE_EXP2 1
#endif
#if __has_builtin(__builtin_amdgcn_mfma_f32_16x16x16bf16_1k)
#define HAVE_MFMA16 1
#endif
#endif

__device__ __forceinline__ float fexp2(float x) {
#ifdef HAVE_EXP2
  return __builtin_amdgcn_exp2f(x);
#else
  return __builtin_exp2f(x);
#endif
}

__device__ __forceinline__ f32x4 mfma16(bf16x4 a, bf16x4 b, f32x4 c) {
#ifdef HAVE_MFMA16
  return __builtin_amdgcn_mfma_f32_16x16x16bf16_1k(a, b, c, 0, 0, 0);
#else
  asm volatile("v_mfma_f32_16x16x16_bf16 %0, %1, %2, %0\n\ts_nop 7\n\ts_nop 7"
               : "+v"(c) : "v"(a), "v"(b));
  return c;
#endif
}

// fp32 -> bf16 for W only (k,q,v now read as fp32 by gemm_proj directly)
__global__ __launch_bounds__(256)
void f2bW(const float* __restrict__ in, unsigned short* __restrict__ out)
{
  const int n4 = (DD * DD) / 4;
  int i = blockIdx.x * 256 + threadIdx.x;
  const int stride = gridDim.x * 256;
  for (; i < n4; i += stride) {
    const float4 f = ((const float4*)in)[i];
    us4 o;
    o[0] = f2bf(f.x); o[1] = f2bf(f.y); o[2] = f2bf(f.z); o[3] = f2bf(f.w);
    ((us4*)out)[i] = o;
  }
}

// Fused K/Q/V projection (r14 geometry: tile 128x64, BK=32, grid (16,96)).
// A is staged as FP32 via global_load_lds (DMA path; r16's reg-staging
// regression avoided) and converted to bf16 at fragment-read time.
// A-tile rows are 128B = 8 x 16B slots; slot swizzle s^(row&7) applied on
// the pre-swizzled global SOURCE (dest linear) and on the read (both sides).
__global__ __launch_bounds__(256)
void gemm_proj(const float* __restrict__ kf, const float* __restrict__ qf,
               const float* __restrict__ vf, const unsigned short* __restrict__ W,
               const float* __restrict__ bias,
               unsigned short* __restrict__ Kp, unsigned short* __restrict__ Qp,
               unsigned short* __restrict__ Vt)
{
  __shared__ float lA[2][128 * 32];            // fp32 A tile: 16KB per buf
  __shared__ unsigned short lB[2][64 * 32];    // bf16 B tile: 4KB per buf
  const int tid = threadIdx.x;
  const int w = tid >> 6, l = tid & 63;
  const int hw = blockIdx.y * gridDim.x + blockIdx.x;     // 0..1535
  const int virt = (hw & 7) * 192 + (hw >> 3);            // bijective XCD swizzle
  const int n0 = (virt & 15) * 64;
  const int my = virt >> 4;                                // 0..95
  const int grp = my >> 5;                                 // 0:K 1:Q 2:V
  const int m0 = (my & 31) * 128;
  const float* A = grp == 0 ? kf : (grp == 1 ? qf : vf);
  const int wr = w >> 1, wc = w & 1;
  const int lg = l >> 4, lc = l & 15;

  f32x4 acc[4][2];
#pragma unroll
  for (int i = 0; i < 4; ++i)
#pragma unroll
    for (int j = 0; j < 2; ++j) acc[i][j] = (f32x4){0.f, 0.f, 0.f, 0.f};

  const int scolb = (((l & 3) ^ ((l >> 2) & 3)) * 16);  // B pre-swizzled 16B slot
  const int asrc = ((l & 7) ^ ((l >> 3) & 7)) << 2;     // A pre-swizzled col (floats)

  auto stage = [&](int buf, int k0) {
    // A: 4 issues x (8 rows x 8 slots) = 128 rows of fp32
#pragma unroll
    for (int cc = 0; cc < 4; ++cc) {
      const int row = (w * 4 + cc) * 8 + (l >> 3);       // 0..127
      gload16(A + (size_t)(m0 + row) * DD + k0 + asrc,
              (char*)lA[buf] + (w * 4 + cc) * 1024);     // dest linear: +l*16
    }
    // B: bf16, 4 slots x 16 rows = 64
    {
      const int row = w * 16 + (l >> 2);
      gload16(W + (size_t)(n0 + row) * DD + k0 + (scolb >> 1), &lB[buf][w * 512]);
    }
  };

  stage(0, 0);
  __syncthreads();
  int cur = 0;
#pragma unroll 1
  for (int kt = 0; kt < 32; ++kt) {
    if (kt < 31) stage(cur ^ 1, (kt + 1) * 32);
    const char* la = (const char*)lA[cur];
    const char* lb = (const char*)lB[cur];
    bf16x8 af[4], bfr[2];
#pragma unroll
    for (int mf = 0; mf < 4; ++mf) {
      const int R = wr * 64 + mf * 16 + lc;
      const f32x4 lo = *(const f32x4*)(la + R * 128 + (((lg * 2 + 0) ^ (R & 7)) << 4));
      const f32x4 hi = *(const f32x4*)(la + R * 128 + (((lg * 2 + 1) ^ (R & 7)) << 4));
      union { u32x4 u; bf16x8 v; } pk;
      pk.u[0] = cvtpk_bf16(lo[0], lo[1]);
      pk.u[1] = cvtpk_bf16(lo[2], lo[3]);
      pk.u[2] = cvtpk_bf16(hi[0], hi[1]);
      pk.u[3] = cvtpk_bf16(hi[2], hi[3]);
      af[mf] = pk.v;
    }
#pragma unroll
    for (int nf = 0; nf < 2; ++nf)
      bfr[nf] = *(const bf16x8*)(lb + (wc * 32 + nf * 16 + lc) * 64 + ((lg * 16) ^ ((lc & 3) << 4)));
#pragma unroll
    for (int mf = 0; mf < 4; ++mf)
#pragma unroll
      for (int nf = 0; nf < 2; ++nf)
        acc[mf][nf] = __builtin_amdgcn_mfma_f32_16x16x32_bf16(af[mf], bfr[nf], acc[mf][nf], 0, 0, 0);
    __syncthreads();
    cur ^= 1;
  }

  // Q gets 1/sqrt(DK) * log2(e) folded in (attn softmax runs in exp2 domain)
  const float scale = (grp == 1) ? 0.125f * 1.4426950408889634f : 1.0f;
#pragma unroll
  for (int nf = 0; nf < 2; ++nf) {
    const int colg = n0 + wc * 32 + nf * 16 + lc;
    const float bv = bias[colg];
#pragma unroll
    for (int mf = 0; mf < 4; ++mf) {
      const int rowg = m0 + wr * 64 + mf * 16 + lg * 4;
      if (grp < 2) {
        unsigned short* C = grp == 0 ? Kp : Qp;
#pragma unroll
        for (int r = 0; r < 4; ++r)
          C[(size_t)(rowg + r) * DD + colg] = f2bf(scale * (acc[mf][nf][r] + bv));
      } else {
        const int bb = rowg >> 11, t = rowg & (TT - 1);
        const int hh = colg >> 6, dk = colg & 63;
        us4 pk;
#pragma unroll
        for (int r = 0; r < 4; ++r) pk[r] = f2bf(acc[mf][nf][r] + bv);
        *(us4*)&Vt[((size_t)((bb * HH + hh) * DKK + dk)) * TT + t] = pk;
      }
    }
  }
}

// Final projection: C(fp32) = A @ W^T + bias; tile 64x64; grid (16,64)=1024.
__global__ __launch_bounds__(256)
void gemm_out(const unsigned short* __restrict__ A, const unsigned short* __restrict__ W,
              const float* __restrict__ bias, float* __restrict__ Cf)
{
  __shared__ unsigned short lA[2][64 * 32];
  __shared__ unsigned short lB[2][64 * 32];
  const int tid = threadIdx.x;
  const int w = tid >> 6, l = tid & 63;
  const int hw = blockIdx.y * gridDim.x + blockIdx.x;
  const int virt = (hw & 7) * 128 + (hw >> 3);
  const int n0 = (virt & 15) * 64, m0 = (virt >> 4) * 64;
  const int wr = w >> 1, wc = w & 1;
  const int lg = l >> 4, lc = l & 15;

  f32x4 acc[2][2];
#pragma unroll
  for (int i = 0; i < 2; ++i)
#pragma unroll
    for (int j = 0; j < 2; ++j) acc[i][j] = (f32x4){0.f, 0.f, 0.f, 0.f};

  const int scolb = (((l & 3) ^ ((l >> 2) & 3)) * 16);

  auto stage = [&](int buf, int k0) {
    const int row = w * 16 + (l >> 2);
    gload16(A + (size_t)(m0 + row) * DD + k0 + (scolb >> 1), &lA[buf][w * 512]);
    gload16(W + (size_t)(n0 + row) * DD + k0 + (scolb >> 1), &lB[buf][w * 512]);
  };

  stage(0, 0);
  __syncthreads();
  int cur = 0;
#pragma unroll 1
  for (int kt = 0; kt < 32; ++kt) {
    if (kt < 31) stage(cur ^ 1, (kt + 1) * 32);
    const char* la = (const char*)lA[cur];
    const char* lb = (const char*)lB[cur];
    bf16x8 af[2], bfr[2];
#pragma unroll
    for (int mf = 0; mf < 2; ++mf)
      af[mf] = *(const bf16x8*)(la + (wr * 32 + mf * 16 + lc) * 64 + ((lg * 16) ^ ((lc & 3) << 4)));
#pragma unroll
    for (int nf = 0; nf < 2; ++nf)
      bfr[nf] = *(const bf16x8*)(lb + (wc * 32 + nf * 16 + lc) * 64 + ((lg * 16) ^ ((lc & 3) << 4)));
#pragma unroll
    for (int mf = 0; mf < 2; ++mf)
#pragma unroll
      for (int nf = 0; nf < 2; ++nf)
        acc[mf][nf] = __builtin_amdgcn_mfma_f32_16x16x32_bf16(af[mf], bfr[nf], acc[mf][nf], 0, 0, 0);
    __syncthreads();
    cur ^= 1;
  }

#pragma unroll
  for (int nf = 0; nf < 2; ++nf) {
    const int colg = n0 + wc * 32 + nf * 16 + lc;
    const float bv = bias[colg];
#pragma unroll
    for (int mf = 0; mf < 2; ++mf) {
      const int rowg = m0 + wr * 32 + mf * 16 + lg * 4;
#pragma unroll
      for (int r = 0; r < 4; ++r)
        Cf[(size_t)(rowg + r) * DD + colg] = acc[mf][nf][r] + bv;
    }
  }
}

// Flash attention — EXACT r13/r14 proven version (53.5 us): swapped-operand
// QK^T, in-register P, exp2-domain softmax, T13 defer-rescale, deferred
// lsum reduce. QBLK=64, grid (32,32), heavy-first.
__global__ __launch_bounds__(256)
void attn(const unsigned short* __restrict__ Qp,
          const unsigned short* __restrict__ Kp,
          const unsigned short* __restrict__ Vt,
          const int* __restrict__ maskp,
          const int* __restrict__ causalp,
          unsigned short* __restrict__ Oc)
{
  __shared__ unsigned short Kl[2][64 * 64];
  __shared__ unsigned short Vl[2][64 * 64];
  const int tid = threadIdx.x;
  const int w = tid >> 6, l = tid & 63;
  const int bh = blockIdx.x;
  const int q0 = (31 - blockIdx.y) * 64;
  const int b = bh >> 4, h = bh & 15;
  const int lg = l >> 4, lc = l & 15;
  const int causal = causalp[0];
  const int qr = q0 + w * 16 + lc;

  bf16x8 qf[2];
  {
    const unsigned short* qp = Qp + (size_t)(b * TT + qr) * DD + h * DKK + lg * 8;
    qf[0] = *(const bf16x8*)qp;
    qf[1] = *(const bf16x8*)(qp + 32);
  }
  f32x4 o[4];
#pragma unroll
  for (int nfo = 0; nfo < 4; ++nfo) o[nfo] = (f32x4){0.f, 0.f, 0.f, 0.f};
  float m = -1e30f, lsum = 0.f;

  const int swz = ((l & 7) ^ (l >> 3)) * 16;
  int kcoff[2], vcoff[4];
#pragma unroll
  for (int kk = 0; kk < 2; ++kk) kcoff[kk] = (kk * 64 + lg * 16) ^ ((lc & 7) << 4);
#pragma unroll
  for (int nfk = 0; nfk < 4; ++nfk) vcoff[nfk] = (nfk * 32 + lg * 8) ^ ((lc & 7) << 4);
  const int rowb = lc * 128;
  const int* mrow = maskp + b * TT;

  auto stage = [&](int buf, int c0) {
#pragma unroll
    for (int cc = 0; cc < 2; ++cc) {
      const int slot = w * 2 + cc;
      const int rr = slot * 8 + (l >> 3);
      gload16(Kp + (size_t)(b * TT + c0 + rr) * DD + h * DKK + (swz >> 1), &Kl[buf][slot * 512]);
      gload16(Vt + (size_t)((b * HH + h) * DKK + rr) * TT + c0 + (swz >> 1), &Vl[buf][slot * 512]);
    }
  };

  const int ntiles = (causal ? (q0 + 64) : TT) >> 6;
  stage(0, 0);
  __syncthreads();
  int cur = 0;
#pragma unroll 1
  for (int t = 0; t < ntiles; ++t) {
    if (t + 1 < ntiles) stage(cur ^ 1, (t + 1) * 64);
    const int c0 = t * 64;
    const char* kl = (const char*)Kl[cur];
    const char* vl = (const char*)Vl[cur];

    f32x4 s[4];
#pragma unroll
    for (int nf = 0; nf < 4; ++nf) s[nf] = (f32x4){0.f, 0.f, 0.f, 0.f};
#pragma unroll
    for (int nf = 0; nf < 4; ++nf)
#pragma unroll
      for (int kk = 0; kk < 2; ++kk) {
        bf16x8 kf = *(const bf16x8*)(kl + rowb + kcoff[kk] + nf * 2048);
        s[nf] = __builtin_amdgcn_mfma_f32_16x16x32_bf16(kf, qf[kk], s[nf], 0, 0, 0);
      }

    const unsigned long long bal = __ballot(mrow[c0 + l] != 0);
    if (bal != ~0ull) {
#pragma unroll
      for (int nf = 0; nf < 4; ++nf) {
        const int4 mv = *(const int4*)&mrow[c0 + nf * 16 + lg * 4];
        const int mvr[4] = {mv.x, mv.y, mv.z, mv.w};
#pragma unroll
        for (int r = 0; r < 4; ++r)
          if (mvr[r] == 0) s[nf][r] = -1e30f;
      }
    }
    if (causal && (t == ntiles - 1)) {
#pragma unroll
      for (int nf = 0; nf < 4; ++nf)
#pragma unroll
        for (int r = 0; r < 4; ++r) {
          const int kg = c0 + nf * 16 + lg * 4 + r;
          if (kg > qr) s[nf][r] = -1e30f;
        }
    }

    float pm = fmaxf(fmaxf(fmaxf(s[0][0], s[0][1]), fmaxf(s[0][2], s[0][3])),
                     fmaxf(fmaxf(s[1][0], s[1][1]), fmaxf(s[1][2], s[1][3])));
    pm = fmaxf(pm, fmaxf(fmaxf(fmaxf(s[2][0], s[2][1]), fmaxf(s[2][2], s[2][3])),
                         fmaxf(fmaxf(s[3][0], s[3][1]), fmaxf(s[3][2], s[3][3]))));
    pm = fmaxf(pm, __shfl_xor(pm, 16, 64));
    pm = fmaxf(pm, __shfl_xor(pm, 32, 64));

    if (!__all((m > -1e28f) && (pm <= m + 8.0f))) {
      const float mn = fmaxf(fmaxf(m, pm), -1e28f);
      const float al = fexp2(m - mn);
      m = mn;
      float alr[4];
#pragma unroll
      for (int r = 0; r < 4; ++r) alr[r] = __shfl(al, lg * 4 + r, 64);
#pragma unroll
      for (int nfo = 0; nfo < 4; ++nfo)
#pragma unroll
        for (int r = 0; r < 4; ++r) o[nfo][r] *= alr[r];
      lsum *= al;
    }

    float ps = 0.f;
    bf16x4 pa[4];
#pragma unroll
    for (int nf = 0; nf < 4; ++nf) {
      const float p0 = fexp2(s[nf][0] - m);
      const float p1 = fexp2(s[nf][1] - m);
      const float p2 = fexp2(s[nf][2] - m);
      const float p3 = fexp2(s[nf][3] - m);
      ps += (p0 + p1) + (p2 + p3);
      union { unsigned int u[2]; bf16x4 v; } pk;
      pk.u[0] = cvtpk_bf16(p0, p1);
      pk.u[1] = cvtpk_bf16(p2, p3);
      pa[nf] = pk.v;
    }
    lsum += ps;

#pragma unroll
    for (int nfo = 0; nfo < 4; ++nfo)
#pragma unroll
      for (int nfk = 0; nfk < 4; ++nfk) {
        bf16x4 vb = *(const bf16x4*)(vl + rowb + vcoff[nfk] + nfo * 2048);
        o[nfo] = mfma16(pa[nfk], vb, o[nfo]);
      }

    __syncthreads();
    cur ^= 1;
  }

  lsum += __shfl_xor(lsum, 16, 64);
  lsum += __shfl_xor(lsum, 32, 64);
  float linv[4];
#pragma unroll
  for (int r = 0; r < 4; ++r) linv[r] = 1.0f / __shfl(lsum, lg * 4 + r, 64);
#pragma unroll
  for (int nfo = 0; nfo < 4; ++nfo) {
    const int dg = h * DKK + nfo * 16 + lc;
#pragma unroll
    for (int r = 0; r < 4; ++r) {
      const int qg = q0 + w * 16 + lg * 4 + r;
      Oc[(size_t)(b * TT + qg) * DD + dg] = f2bf(o[nfo][r] * linv[r]);
    }
  }
}

extern "C" void kernel_launch(void* const* d_in, const int* in_sizes, int n_in,
                              void* d_out, int out_size, void* d_ws, size_t ws_size,
                              hipStream_t stream)
{
  (void)in_sizes; (void)n_in; (void)out_size; (void)ws_size;
  const float* kf = (const float*)d_in[0];
  const float* qf = (const float*)d_in[1];
  const float* vf = (const float*)d_in[2];
  const int* mask = (const int*)d_in[3];
  const int* causal = (const int*)d_in[4];
  const float* Wf = (const float*)d_in[5];
  const float* bf = (const float*)d_in[6];

  const size_t MB = 1024 * 1024;
  char* ws = (char*)d_ws;
  unsigned short* Wb = (unsigned short*)(ws);                 // 2 MiB
  unsigned short* Kp = (unsigned short*)(ws + 2 * MB);        // 8 MiB
  unsigned short* Qp = (unsigned short*)(ws + 10 * MB);       // 8 MiB
  unsigned short* Vt = (unsigned short*)(ws + 18 * MB);       // 8 MiB
  unsigned short* Oc = (unsigned short*)(ws + 26 * MB);       // 8 MiB

  f2bW<<<dim3(512), dim3(256), 0, stream>>>(Wf, Wb);
  gemm_proj<<<dim3(16, 96), dim3(256), 0, stream>>>(kf, qf, vf, Wb, bf, Kp, Qp, Vt);
  attn<<<dim3(32, 32), dim3(256), 0, stream>>>(Qp, Kp, Vt, mask, causal, Oc);
  gemm_out<<<dim3(16, 64), dim3(256), 0, stream>>>(Oc, Wb, bf, (float*)d_out);
}

// Round 21
// 127.578 us; speedup vs baseline: 1.1227x; 1.0124x over previous
//
#include <hip/hip_runtime.h>

#define TT 2048
#define DD 1024
#define HH 16
#define DKK 64
#define BB 2

typedef __attribute__((ext_vector_type(8))) short bf16x8;
typedef __attribute__((ext_vector_type(4))) short bf16x4;
typedef __attribute__((ext_vector_type(4))) float f32x4;
typedef __attribute__((ext_vector_type(4))) unsigned short us4;

__device__ __forceinline__ unsigned short f2bf(float f) {
  union { float f; unsigned int i; } v; v.f = f;
  unsigned int x = v.i;
  return (unsigned short)((x + 0x7fffu + ((x >> 16) & 1u)) >> 16);
}
__device__ __forceinline__ unsigned int cvtpk_bf16(float lo, float hi) {
  unsigned int r;
  asm("v_cvt_pk_bf16_f32 %0, %1, %2" : "=v"(r) : "v"(lo), "v"(hi));
  return r;
}
__device__ __forceinline__ void gload16(const void* g, void* l) {
  __builtin_amdgcn_global_load_lds((const __attribute__((address_space(1))) void*)g,
                                   (__attribute__((address_space(3))) void*)l,
                                   16, 0, 0);
}

#if defined(__has_builtin)
#if __has_builtin(__builtin_amdgcn_exp2f)
#define HAVE_EXP2 1
#endif
#if __has_builtin(__builtin_amdgcn_mfma_f32_16x16x16bf16_1k)
#define HAVE_MFMA16 1
#endif
#endif

__device__ __forceinline__ float fexp2(float x) {
#ifdef HAVE_EXP2
  return __builtin_amdgcn_exp2f(x);
#else
  return __builtin_exp2f(x);
#endif
}

__device__ __forceinline__ f32x4 mfma16(bf16x4 a, bf16x4 b, f32x4 c) {
#ifdef HAVE_MFMA16
  return __builtin_amdgcn_mfma_f32_16x16x16bf16_1k(a, b, c, 0, 0, 0);
#else
  asm volatile("v_mfma_f32_16x16x16_bf16 %0, %1, %2, %0\n\ts_nop 7\n\ts_nop 7"
               : "+v"(c) : "v"(a), "v"(b));
  return c;
#endif
}

// fp32 -> bf16 for k,q,v,W in one dispatch (HBM-BW-bound, ~12us at ceiling;
// keeping this separate beats all in-GEMM conversion variants: r16, r20)
__global__ __launch_bounds__(256)
void f2b_all(const float* __restrict__ k, const float* __restrict__ q,
             const float* __restrict__ v, const float* __restrict__ W,
             unsigned short* __restrict__ kb, unsigned short* __restrict__ qb,
             unsigned short* __restrict__ vb, unsigned short* __restrict__ Wb)
{
  const int n1 = (BB * TT * DD) / 4;   // 1048576 float4s per tensor
  const int nW = (DD * DD) / 4;        // 262144
  const int total = 3 * n1 + nW;
  int i = blockIdx.x * 256 + threadIdx.x;
  const int stride = gridDim.x * 256;
  for (; i < total; i += stride) {
    const float* src; unsigned short* dst; int j = i;
    if (j < n1)            { src = k; dst = kb; }
    else if (j < 2 * n1)   { src = q; dst = qb; j -= n1; }
    else if (j < 3 * n1)   { src = v; dst = vb; j -= 2 * n1; }
    else                   { src = W; dst = Wb; j -= 3 * n1; }
    const float4 f = ((const float4*)src)[j];
    us4 o;
    o[0] = f2bf(f.x); o[1] = f2bf(f.y); o[2] = f2bf(f.z); o[3] = f2bf(f.w);
    ((us4*)dst)[j] = o;
  }
}

// ---- GEMM machinery: 2-barrier double-buffered K-loop, BK=32 ----
// gemm_proj 128x64 (1536 blocks), gemm_out 64x64 (1024 blocks) — the
// measured sweet spots (r14; 64x64 proj and fp32-A staging both regressed).
// LDS rows 64B; XOR-swizzle (row&3)<<4 via pre-swizzled global source +
// linear gload_lds dest. Bijective XCD swizzle (n fast).

// Fused K/Q/V projection: tile 128(m) x 64(n); grid (16, 96) = 1536 blocks.
__global__ __launch_bounds__(256)
void gemm_proj(const unsigned short* __restrict__ kb, const unsigned short* __restrict__ qb,
               const unsigned short* __restrict__ vb, const unsigned short* __restrict__ W,
               const float* __restrict__ bias,
               unsigned short* __restrict__ Kp, unsigned short* __restrict__ Qp,
               unsigned short* __restrict__ Vt)
{
  __shared__ unsigned short lA[2][128 * 32];
  __shared__ unsigned short lB[2][64 * 32];
  const int tid = threadIdx.x;
  const int w = tid >> 6, l = tid & 63;
  const int hw = blockIdx.y * gridDim.x + blockIdx.x;     // 0..1535
  const int virt = (hw & 7) * 192 + (hw >> 3);            // bijective XCD swizzle
  const int n0 = (virt & 15) * 64;                        // 16 n-blocks
  const int my = virt >> 4;                               // 0..95 m-strips
  const int grp = my >> 5;                                // 0:K 1:Q 2:V
  const int m0 = (my & 31) * 128;
  const unsigned short* A = grp == 0 ? kb : (grp == 1 ? qb : vb);
  const int wr = w >> 1, wc = w & 1;
  const int lg = l >> 4, lc = l & 15;

  f32x4 acc[4][2];
#pragma unroll
  for (int i = 0; i < 4; ++i)
#pragma unroll
    for (int j = 0; j < 2; ++j) acc[i][j] = (f32x4){0.f, 0.f, 0.f, 0.f};

  const int scolb = (((l & 3) ^ ((l >> 2) & 3)) * 16);  // pre-swizzled source slot

  auto stage = [&](int buf, int k0) {
#pragma unroll
    for (int cc = 0; cc < 2; ++cc) {              // A: 8 slots x 16 rows = 128
      const int slot = w * 2 + cc;
      const int row = slot * 16 + (l >> 2);
      gload16(A + (size_t)(m0 + row) * DD + k0 + (scolb >> 1), &lA[buf][slot * 512]);
    }
    {                                             // B: 4 slots x 16 rows = 64
      const int row = w * 16 + (l >> 2);
      gload16(W + (size_t)(n0 + row) * DD + k0 + (scolb >> 1), &lB[buf][w * 512]);
    }
  };

  stage(0, 0);
  __syncthreads();
  int cur = 0;
#pragma unroll 1
  for (int kt = 0; kt < 32; ++kt) {
    if (kt < 31) stage(cur ^ 1, (kt + 1) * 32);
    const char* la = (const char*)lA[cur];
    const char* lb = (const char*)lB[cur];
    bf16x8 af[4], bfr[2];
#pragma unroll
    for (int mf = 0; mf < 4; ++mf)
      af[mf] = *(const bf16x8*)(la + (wr * 64 + mf * 16 + lc) * 64 + ((lg * 16) ^ ((lc & 3) << 4)));
#pragma unroll
    for (int nf = 0; nf < 2; ++nf)
      bfr[nf] = *(const bf16x8*)(lb + (wc * 32 + nf * 16 + lc) * 64 + ((lg * 16) ^ ((lc & 3) << 4)));
#pragma unroll
    for (int mf = 0; mf < 4; ++mf)
#pragma unroll
      for (int nf = 0; nf < 2; ++nf)
        acc[mf][nf] = __builtin_amdgcn_mfma_f32_16x16x32_bf16(af[mf], bfr[nf], acc[mf][nf], 0, 0, 0);
    __syncthreads();
    cur ^= 1;
  }

  // Q gets 1/sqrt(DK) * log2(e) folded in (attn softmax runs in exp2 domain)
  const float scale = (grp == 1) ? 0.125f * 1.4426950408889634f : 1.0f;
#pragma unroll
  for (int nf = 0; nf < 2; ++nf) {
    const int colg = n0 + wc * 32 + nf * 16 + lc;
    const float bv = bias[colg];
#pragma unroll
    for (int mf = 0; mf < 4; ++mf) {
      const int rowg = m0 + wr * 64 + mf * 16 + lg * 4;
      if (grp < 2) {
        unsigned short* C = grp == 0 ? Kp : Qp;
#pragma unroll
        for (int r = 0; r < 4; ++r)
          C[(size_t)(rowg + r) * DD + colg] = f2bf(scale * (acc[mf][nf][r] + bv));
      } else {
        const int bb = rowg >> 11, t = rowg & (TT - 1);
        const int hh = colg >> 6, dk = colg & 63;
        us4 pk;
#pragma unroll
        for (int r = 0; r < 4; ++r) pk[r] = f2bf(acc[mf][nf][r] + bv);
        *(us4*)&Vt[((size_t)((bb * HH + hh) * DKK + dk)) * TT + t] = pk;
      }
    }
  }
}

// Final projection: C(fp32) = A @ W^T + bias; tile 64x64; grid (16,64)=1024.
__global__ __launch_bounds__(256)
void gemm_out(const unsigned short* __restrict__ A, const unsigned short* __restrict__ W,
              const float* __restrict__ bias, float* __restrict__ Cf)
{
  __shared__ unsigned short lA[2][64 * 32];
  __shared__ unsigned short lB[2][64 * 32];
  const int tid = threadIdx.x;
  const int w = tid >> 6, l = tid & 63;
  const int hw = blockIdx.y * gridDim.x + blockIdx.x;     // 0..1023
  const int virt = (hw & 7) * 128 + (hw >> 3);            // bijective XCD swizzle
  const int n0 = (virt & 15) * 64, m0 = (virt >> 4) * 64;
  const int wr = w >> 1, wc = w & 1;
  const int lg = l >> 4, lc = l & 15;

  f32x4 acc[2][2];
#pragma unroll
  for (int i = 0; i < 2; ++i)
#pragma unroll
    for (int j = 0; j < 2; ++j) acc[i][j] = (f32x4){0.f, 0.f, 0.f, 0.f};

  const int scolb = (((l & 3) ^ ((l >> 2) & 3)) * 16);

  auto stage = [&](int buf, int k0) {
    const int row = w * 16 + (l >> 2);                    // 4 slots x 16 rows
    gload16(A + (size_t)(m0 + row) * DD + k0 + (scolb >> 1), &lA[buf][w * 512]);
    gload16(W + (size_t)(n0 + row) * DD + k0 + (scolb >> 1), &lB[buf][w * 512]);
  };

  stage(0, 0);
  __syncthreads();
  int cur = 0;
#pragma unroll 1
  for (int kt = 0; kt < 32; ++kt) {
    if (kt < 31) stage(cur ^ 1, (kt + 1) * 32);
    const char* la = (const char*)lA[cur];
    const char* lb = (const char*)lB[cur];
    bf16x8 af[2], bfr[2];
#pragma unroll
    for (int mf = 0; mf < 2; ++mf)
      af[mf] = *(const bf16x8*)(la + (wr * 32 + mf * 16 + lc) * 64 + ((lg * 16) ^ ((lc & 3) << 4)));
#pragma unroll
    for (int nf = 0; nf < 2; ++nf)
      bfr[nf] = *(const bf16x8*)(lb + (wc * 32 + nf * 16 + lc) * 64 + ((lg * 16) ^ ((lc & 3) << 4)));
#pragma unroll
    for (int mf = 0; mf < 2; ++mf)
#pragma unroll
      for (int nf = 0; nf < 2; ++nf)
        acc[mf][nf] = __builtin_amdgcn_mfma_f32_16x16x32_bf16(af[mf], bfr[nf], acc[mf][nf], 0, 0, 0);
    __syncthreads();
    cur ^= 1;
  }

#pragma unroll
  for (int nf = 0; nf < 2; ++nf) {
    const int colg = n0 + wc * 32 + nf * 16 + lc;
    const float bv = bias[colg];
#pragma unroll
    for (int mf = 0; mf < 2; ++mf) {
      const int rowg = m0 + wr * 32 + mf * 16 + lg * 4;
#pragma unroll
      for (int r = 0; r < 4; ++r)
        Cf[(size_t)(rowg + r) * DD + colg] = acc[mf][nf][r] + bv;
    }
  }
}

// Flash attention (r13 proven version, 53.5 us): swapped-operand QK^T,
// in-register P, exp2-domain softmax, T13 defer-rescale, deferred lsum
// reduce. QBLK=64, grid (32,32), heavy-first.
__global__ __launch_bounds__(256)
void attn(const unsigned short* __restrict__ Qp,
          const unsigned short* __restrict__ Kp,
          const unsigned short* __restrict__ Vt,
          const int* __restrict__ maskp,
          const int* __restrict__ causalp,
          unsigned short* __restrict__ Oc)
{
  __shared__ unsigned short Kl[2][64 * 64];
  __shared__ unsigned short Vl[2][64 * 64];
  const int tid = threadIdx.x;
  const int w = tid >> 6, l = tid & 63;
  const int bh = blockIdx.x;
  const int q0 = (31 - blockIdx.y) * 64;
  const int b = bh >> 4, h = bh & 15;
  const int lg = l >> 4, lc = l & 15;
  const int causal = causalp[0];
  const int qr = q0 + w * 16 + lc;          // this lane's q-row

  bf16x8 qf[2];
  {
    const unsigned short* qp = Qp + (size_t)(b * TT + qr) * DD + h * DKK + lg * 8;
    qf[0] = *(const bf16x8*)qp;
    qf[1] = *(const bf16x8*)(qp + 32);
  }
  f32x4 o[4];
#pragma unroll
  for (int nfo = 0; nfo < 4; ++nfo) o[nfo] = (f32x4){0.f, 0.f, 0.f, 0.f};
  float m = -1e30f, lsum = 0.f;              // lsum: per-lane partial

  const int swz = ((l & 7) ^ (l >> 3)) * 16;
  int kcoff[2], vcoff[4];
#pragma unroll
  for (int kk = 0; kk < 2; ++kk) kcoff[kk] = (kk * 64 + lg * 16) ^ ((lc & 7) << 4);
#pragma unroll
  for (int nfk = 0; nfk < 4; ++nfk) vcoff[nfk] = (nfk * 32 + lg * 8) ^ ((lc & 7) << 4);
  const int rowb = lc * 128;
  const int* mrow = maskp + b * TT;

  auto stage = [&](int buf, int c0) {
#pragma unroll
    for (int cc = 0; cc < 2; ++cc) {
      const int slot = w * 2 + cc;
      const int rr = slot * 8 + (l >> 3);
      gload16(Kp + (size_t)(b * TT + c0 + rr) * DD + h * DKK + (swz >> 1), &Kl[buf][slot * 512]);
      gload16(Vt + (size_t)((b * HH + h) * DKK + rr) * TT + c0 + (swz >> 1), &Vl[buf][slot * 512]);
    }
  };

  const int ntiles = (causal ? (q0 + 64) : TT) >> 6;
  stage(0, 0);
  __syncthreads();
  int cur = 0;
#pragma unroll 1
  for (int t = 0; t < ntiles; ++t) {
    if (t + 1 < ntiles) stage(cur ^ 1, (t + 1) * 64);
    const int c0 = t * 64;
    const char* kl = (const char*)Kl[cur];
    const char* vl = (const char*)Vl[cur];

    f32x4 s[4];
#pragma unroll
    for (int nf = 0; nf < 4; ++nf) s[nf] = (f32x4){0.f, 0.f, 0.f, 0.f};
#pragma unroll
    for (int nf = 0; nf < 4; ++nf)
#pragma unroll
      for (int kk = 0; kk < 2; ++kk) {
        bf16x8 kf = *(const bf16x8*)(kl + rowb + kcoff[kk] + nf * 2048);
        s[nf] = __builtin_amdgcn_mfma_f32_16x16x32_bf16(kf, qf[kk], s[nf], 0, 0, 0);
      }

    const unsigned long long bal = __ballot(mrow[c0 + l] != 0);
    if (bal != ~0ull) {
#pragma unroll
      for (int nf = 0; nf < 4; ++nf) {
        const int4 mv = *(const int4*)&mrow[c0 + nf * 16 + lg * 4];
        const int mvr[4] = {mv.x, mv.y, mv.z, mv.w};
#pragma unroll
        for (int r = 0; r < 4; ++r)
          if (mvr[r] == 0) s[nf][r] = -1e30f;
      }
    }
    if (causal && (t == ntiles - 1)) {
#pragma unroll
      for (int nf = 0; nf < 4; ++nf)
#pragma unroll
        for (int r = 0; r < 4; ++r) {
          const int kg = c0 + nf * 16 + lg * 4 + r;
          if (kg > qr) s[nf][r] = -1e30f;
        }
    }

    float pm = fmaxf(fmaxf(fmaxf(s[0][0], s[0][1]), fmaxf(s[0][2], s[0][3])),
                     fmaxf(fmaxf(s[1][0], s[1][1]), fmaxf(s[1][2], s[1][3])));
    pm = fmaxf(pm, fmaxf(fmaxf(fmaxf(s[2][0], s[2][1]), fmaxf(s[2][2], s[2][3])),
                         fmaxf(fmaxf(s[3][0], s[3][1]), fmaxf(s[3][2], s[3][3]))));
    pm = fmaxf(pm, __shfl_xor(pm, 16, 64));
    pm = fmaxf(pm, __shfl_xor(pm, 32, 64));

    // T13 defer-rescale
    if (!__all((m > -1e28f) && (pm <= m + 8.0f))) {
      const float mn = fmaxf(fmaxf(m, pm), -1e28f);
      const float al = fexp2(m - mn);
      m = mn;
      float alr[4];
#pragma unroll
      for (int r = 0; r < 4; ++r) alr[r] = __shfl(al, lg * 4 + r, 64);
#pragma unroll
      for (int nfo = 0; nfo < 4; ++nfo)
#pragma unroll
        for (int r = 0; r < 4; ++r) o[nfo][r] *= alr[r];
      lsum *= al;
    }

    float ps = 0.f;
    bf16x4 pa[4];
#pragma unroll
    for (int nf = 0; nf < 4; ++nf) {
      const float p0 = fexp2(s[nf][0] - m);
      const float p1 = fexp2(s[nf][1] - m);
      const float p2 = fexp2(s[nf][2] - m);
      const float p3 = fexp2(s[nf][3] - m);
      ps += (p0 + p1) + (p2 + p3);
      union { unsigned int u[2]; bf16x4 v; } pk;
      pk.u[0] = cvtpk_bf16(p0, p1);
      pk.u[1] = cvtpk_bf16(p2, p3);
      pa[nf] = pk.v;
    }
    lsum += ps;   // per-lane partial; lg-reduce deferred to epilogue

#pragma unroll
    for (int nfo = 0; nfo < 4; ++nfo)
#pragma unroll
      for (int nfk = 0; nfk < 4; ++nfk) {
        bf16x4 vb = *(const bf16x4*)(vl + rowb + vcoff[nfk] + nfo * 2048);
        o[nfo] = mfma16(pa[nfk], vb, o[nfo]);
      }

    __syncthreads();
    cur ^= 1;
  }

  lsum += __shfl_xor(lsum, 16, 64);
  lsum += __shfl_xor(lsum, 32, 64);
  float linv[4];
#pragma unroll
  for (int r = 0; r < 4; ++r) linv[r] = 1.0f / __shfl(lsum, lg * 4 + r, 64);
#pragma unroll
  for (int nfo = 0; nfo < 4; ++nfo) {
    const int dg = h * DKK + nfo * 16 + lc;
#pragma unroll
    for (int r = 0; r < 4; ++r) {
      const int qg = q0 + w * 16 + lg * 4 + r;
      Oc[(size_t)(b * TT + qg) * DD + dg] = f2bf(o[nfo][r] * linv[r]);
    }
  }
}

extern "C" void kernel_launch(void* const* d_in, const int* in_sizes, int n_in,
                              void* d_out, int out_size, void* d_ws, size_t ws_size,
                              hipStream_t stream)
{
  (void)in_sizes; (void)n_in; (void)out_size; (void)ws_size;
  const float* kf = (const float*)d_in[0];
  const float* qf = (const float*)d_in[1];
  const float* vf = (const float*)d_in[2];
  const int* mask = (const int*)d_in[3];
  const int* causal = (const int*)d_in[4];
  const float* Wf = (const float*)d_in[5];
  const float* bf = (const float*)d_in[6];

  const size_t MB = 1024 * 1024;
  char* ws = (char*)d_ws;
  unsigned short* kb = (unsigned short*)(ws);                 // 8 MiB
  unsigned short* qb = (unsigned short*)(ws + 8 * MB);        // 8 MiB
  unsigned short* vb = (unsigned short*)(ws + 16 * MB);       // 8 MiB
  unsigned short* Wb = (unsigned short*)(ws + 24 * MB);       // 2 MiB
  unsigned short* Kp = (unsigned short*)(ws + 26 * MB);       // 8 MiB
  unsigned short* Qp = (unsigned short*)(ws + 34 * MB);       // 8 MiB
  unsigned short* Vt = (unsigned short*)(ws + 42 * MB);       // 8 MiB
  unsigned short* Oc = kb;  // kb dead after projections

  f2b_all<<<dim3(2048), dim3(256), 0, stream>>>(kf, qf, vf, Wf, kb, qb, vb, Wb);
  gemm_proj<<<dim3(16, 96), dim3(256), 0, stream>>>(kb, qb, vb, Wb, bf, Kp, Qp, Vt);
  attn<<<dim3(32, 32), dim3(256), 0, stream>>>(Qp, Kp, Vt, mask, causal, Oc);
  gemm_out<<<dim3(16, 64), dim3(256), 0, stream>>>(Oc, Wb, bf, (float*)d_out);
}